// Round 4
// baseline (547.817 us; speedup 1.0000x reference)
//
#include <hip/hip_runtime.h>
#include <cstdint>

typedef unsigned short u16;
typedef unsigned int u32;

#define AS1 __attribute__((address_space(1)))
#define AS3 __attribute__((address_space(3)))

typedef _Float16 f16x8 __attribute__((ext_vector_type(8)));
typedef float f32x4 __attribute__((ext_vector_type(4)));

static constexpr int Bb = 2, Ss = 4096, Dd = 1024, Ff = 4096;
static constexpr int Mtok = Bb * Ss;          // 8192
static constexpr int NCH = 256;               // scan chunks per sequence
static constexpr int TCH = Ss / NCH;          // 16 steps per chunk
static constexpr int PW = 6144;               // fused projection width / pcat row stride

__device__ __forceinline__ float h2f(u16 u) {
    union { u16 u; _Float16 h; } w; w.u = u; return (float)w.h;
}
__device__ __forceinline__ u16 f2h(float f) {
    union { _Float16 h; u16 u; } w; w.h = (_Float16)f; return w.u;
}

// fast gelu(tanh) == v * sigmoid(1.595769122*(v + 0.044715 v^3))  (exact identity)
__device__ __forceinline__ float gelu_fast(float v) {
    float u = 1.5957691216057308f * (v + 0.044715f * v * v * v);
    return v / (1.f + __expf(-u));
}

// async global->LDS, 16 B per lane (m97 pattern; addrspacecast via C-cast)
__device__ __forceinline__ void gload_lds16(const u16* g, u16* l) {
    __builtin_amdgcn_global_load_lds((const AS1 u32*)g, (AS3 u32*)l, 16, 0, 0);
}

// ============ fused prep: x->fp16 + all 8 weight transposes, ONE launch ============
// blocks [0,8192): cvt x (1024 f32/block)
// then 32x32 transpose tiles: Wq 1024, Wk 1024, Wv 1024, Wa 2048, Wg 1024,
// Wo 1024, W1 4096, W2 4096  (total grid 23552)
__global__ __launch_bounds__(256) void prep_fused(
    const float* __restrict__ x, u16* __restrict__ xb,
    const float* __restrict__ Wq, const float* __restrict__ Wk,
    const float* __restrict__ Wv, const float* __restrict__ Wa,
    const float* __restrict__ Wg, const float* __restrict__ Wo,
    const float* __restrict__ W1, const float* __restrict__ W2,
    u16* __restrict__ WTcat, u16* __restrict__ WTo,
    u16* __restrict__ WT1, u16* __restrict__ WT2) {
    __shared__ u16 t[32][33];
    const int tid = threadIdx.x;
    const int idx = blockIdx.x;
    if (idx < 8192) {
        const long i = ((long)idx * 256 + tid) * 4;
        float4 f = *(const float4*)(x + i);
        ushort4 o;
        o.x = f2h(f.x); o.y = f2h(f.y); o.z = f2h(f.z); o.w = f2h(f.w);
        *(ushort4*)(xb + i) = o;
        return;
    }
    const float* src; u16* dst; int K, N, ti;
    if (idx < 9216)       { src = Wq; dst = WTcat;             K = 1024; N = 1024; ti = idx - 8192; }
    else if (idx < 10240) { src = Wk; dst = WTcat + (1u << 20); K = 1024; N = 1024; ti = idx - 9216; }
    else if (idx < 11264) { src = Wv; dst = WTcat + (2u << 20); K = 1024; N = 1024; ti = idx - 10240; }
    else if (idx < 13312) { src = Wa; dst = WTcat + (3u << 20); K = 1024; N = 2048; ti = idx - 11264; }
    else if (idx < 14336) { src = Wg; dst = WTcat + (5u << 20); K = 1024; N = 1024; ti = idx - 13312; }
    else if (idx < 15360) { src = Wo; dst = WTo;               K = 1024; N = 1024; ti = idx - 14336; }
    else if (idx < 19456) { src = W1; dst = WT1;               K = 1024; N = 4096; ti = idx - 15360; }
    else                  { src = W2; dst = WT2;               K = 4096; N = 1024; ti = idx - 19456; }
    const int tiles_x = N >> 5;
    const int bx = ti % tiles_x, by = ti / tiles_x;
    const int n0 = bx << 5, k0 = by << 5;
    const int tx = tid & 31, ty = tid >> 5;   // ty 0..7
#pragma unroll
    for (int r = 0; r < 4; r++) {
        const int row = ty + r * 8;
        t[row][tx] = f2h(src[(long)(k0 + row) * N + n0 + tx]);
    }
    __syncthreads();
    // packed u32 stores: lane owns 2 consecutive k (cx, cx+1) for rows ry, ry+16
    const int cx = (tid & 15) << 1;
    const int ry = tid >> 4;                  // 0..15
#pragma unroll
    for (int r = 0; r < 2; r++) {
        const int row = ry + r * 16;
        u32 v = (u32)t[cx][row] | ((u32)t[cx + 1][row] << 16);
        *(u32*)(dst + (long)(n0 + row) * K + k0 + cx) = v;
    }
}

// ===================== 256x256 8-phase GEMM, PERSISTENT (m201-style) =====================
// BM=BN=256, BK=64, 512 threads = 8 waves (2M x 4N), per-wave output 128x64.
// LDS 128 KiB: 2 dbuf x (A[256][64] + B[256][64]) fp16, XOR-swizzled 16B chunks:
//   element (row,k) lives at chunk (k>>3) ^ (row&7)  -> conflict-free ds_read_b128.
// global_load_lds writes linearly -> pre-swizzle the global SOURCE column (rule 21).
// PERSISTENT: each block owns tpb = total_tiles/gridDim.x output tiles; the tail
// staging of tile t redirects to tile t+1's kt0/kt1 (nt even => buffer parity is
// continuous across the seam), so the pipeline never drains between tiles.
// Steady in-flight at iter top: [B(g):4, A(g):4, B(g+1):4] -> vmcnt(4).
template <int EPI>
__global__ __launch_bounds__(512, 2) void gemm8p(const u16* __restrict__ A,
                                                 const u16* __restrict__ BT,
                                                 u16* __restrict__ C,
                                                 const float* __restrict__ bias,
                                                 int M, int N, int K,
                                                 int lda, int ldc) {
    extern __shared__ u16 lds[];  // [buf0: A 16384 | B 16384][buf1: A | B] u16
    const int tid = threadIdx.x;

    const int ntn = N >> 8;
    const int total = (M >> 8) * ntn;     // output tiles (multiple of 8 and of grid)
    const int tpb = total / (int)gridDim.x;
    const int cpx = total >> 3;           // XCD-bijective swizzle chunk

    // ---- staging thread mapping (pre-swizzled global source) ----
    const int srow = tid >> 3;                          // 0..63 within a 64-row round
    const int scol = ((tid & 7) ^ (srow & 7)) << 3;     // swizzled k-chunk * 8
    const long lda64 = (long)lda << 6;   // 64 rows of A
    const long ldb64 = (long)K << 6;     // 64 rows of B^T

    const int nt = K >> 6;

    auto bases_for = [&](int t, int& tm, int& tn, const u16*& Ab, const u16*& Bb) {
        if (t > tpb - 1) t = tpb - 1;
        const int ti = (int)blockIdx.x + t * (int)gridDim.x;
        const int b = (ti & 7) * cpx + (ti >> 3);
        tm = (b / ntn) << 8;
        tn = (b % ntn) << 8;
        Ab = A + (long)(tm + srow) * lda + scol;
        Bb = BT + (long)(tn + srow) * (long)K + scol;
    };

    auto stA = [&](u16* bufbase, int h, const u16* Ab, int kt) {
        u16* d = bufbase + h * 8192 + tid * 8;
        const u16* g = Ab + (long)(h * 128) * lda + (kt << 6);
        gload_lds16(g, d);
        gload_lds16(g + lda64, d + 4096);
    };
    auto stB = [&](u16* bufbase, int h, const u16* Bb, int kt) {
        u16* d = bufbase + 16384 + h * 8192 + tid * 8;
        const u16* g = Bb + (long)(h * 128) * (long)K + (kt << 6);
        gload_lds16(g, d);
        gload_lds16(g + ldb64, d + 4096);
    };

    // ---- fragment read addresses (swizzled) ----
    const int wid = tid >> 6, lane = tid & 63;
    const int r16 = lane & 15, q = lane >> 4;
    const int wm = (wid >> 2) * 128;     // 0 / 128
    const int wn = (wid & 3) * 64;       // 0 / 64 / 128 / 192
    const int r7 = r16 & 7;
    const int cx0 = (q ^ r7) << 3;        // k-half 0 chunk offset (u16)
    const int cx1 = ((4 | q) ^ r7) << 3;  // k-half 1
    const int aoff = (wm + r16) * 64;
    const int boff = 16384 + (wn + r16) * 64;

    f32x4 acc[8][4];
#pragma unroll
    for (int i = 0; i < 8; i++)
#pragma unroll
        for (int j = 0; j < 4; j++) acc[i][j] = (f32x4){0.f, 0.f, 0.f, 0.f};

    int tmc, tnc, tmn, tnn;
    const u16 *Ac, *Bc, *An, *Bn;
    bases_for(0, tmc, tnc, Ac, Bc);
    bases_for(1, tmn, tnn, An, Bn);

    // ---- prologue: buf0 <- tile0.kt0 (A,B), buf1.B <- tile0.kt1 (nt >= 2) ----
    stA(lds, 0, Ac, 0);
    stA(lds, 1, Ac, 0);
    stB(lds, 0, Bc, 0);
    stB(lds, 1, Bc, 0);
    stB(lds + 32768, 0, Bc, 1);
    stB(lds + 32768, 1, Bc, 1);

    for (int t = 0; t < tpb; ++t) {
        for (int it = 0; it < nt; ++it) {
            u16* sb = lds + ((it & 1) << 15);          // current buffer (nt even)
            u16* so = lds + (((it & 1) ^ 1) << 15);    // other buffer

            asm volatile("s_waitcnt vmcnt(4)" ::: "memory");
            __builtin_amdgcn_s_barrier();

            f16x8 vb[4][2];
#pragma unroll
            for (int ni = 0; ni < 4; ni++) {
                vb[ni][0] = *(const f16x8*)(sb + boff + ni * 1024 + cx0);
                vb[ni][1] = *(const f16x8*)(sb + boff + ni * 1024 + cx1);
            }

#pragma unroll
            for (int p = 0; p < 4; ++p) {
                f16x8 pa[2][2];
#pragma unroll
                for (int m2 = 0; m2 < 2; m2++) {
                    pa[m2][0] = *(const f16x8*)(sb + aoff + (2 * p + m2) * 1024 + cx0);
                    pa[m2][1] = *(const f16x8*)(sb + aoff + (2 * p + m2) * 1024 + cx1);
                }
                // staging: A one K-step ahead, B two ahead; tail redirects to next tile
                if (p == 0) {
                    if (it + 1 < nt) stA(so, 0, Ac, it + 1);
                    else             stA(so, 0, An, 0);
                } else if (p == 1) {
                    if (it + 1 < nt) stA(so, 1, Ac, it + 1);
                    else             stA(so, 1, An, 0);
                } else if (p == 2) {
                    if (it + 2 < nt) stB(sb, 0, Bc, it + 2);
                    else             stB(sb, 0, Bn, it + 2 - nt);
                } else {
                    if (it + 2 < nt) stB(sb, 1, Bc, it + 2);
                    else             stB(sb, 1, Bn, it + 2 - nt);
                }
                __builtin_amdgcn_s_barrier();
                asm volatile("s_waitcnt lgkmcnt(0)" ::: "memory");
                __builtin_amdgcn_s_setprio(1);
#pragma unroll
                for (int m2 = 0; m2 < 2; m2++)
#pragma unroll
                    for (int ni = 0; ni < 4; ni++) {
                        acc[2 * p + m2][ni] = __builtin_amdgcn_mfma_f32_16x16x32_f16(
                            pa[m2][0], vb[ni][0], acc[2 * p + m2][ni], 0, 0, 0);
                        acc[2 * p + m2][ni] = __builtin_amdgcn_mfma_f32_16x16x32_f16(
                            pa[m2][1], vb[ni][1], acc[2 * p + m2][ni], 0, 0, 0);
                    }
                __builtin_amdgcn_s_setprio(0);
                __builtin_amdgcn_s_barrier();
            }
        }

        // ---- epilogue for tile t (stores drain under the next tile's vmcnt) ----
#pragma unroll
        for (int mi = 0; mi < 8; mi++) {
#pragma unroll
            for (int ni = 0; ni < 4; ni++) {
                const int gcol = tnc + wn + ni * 16 + r16;
                float bv = 0.f;
                if (EPI) bv = bias[gcol];
#pragma unroll
                for (int j = 0; j < 4; j++) {
                    const int grow = tmc + wm + mi * 16 + q * 4 + j;
                    float v = acc[mi][ni][j];
                    if (EPI) v += bv;
                    if (EPI == 1) v = gelu_fast(v);
                    C[(long)grow * ldc + gcol] = f2h(v);
                    acc[mi][ni][j] = 0.f;
                }
            }
        }
        tmc = tmn; tnc = tnn; Ac = An; Bc = Bn;
        bases_for(t + 2, tmn, tnn, An, Bn);
    }

    asm volatile("s_waitcnt vmcnt(0)" ::: "memory");
}

// ================== 256x128 8-phase GEMM variant (narrow-N: Wo, FFN2) ==================
// BM=256, BN=128, BK=64, 512 threads = 8 waves (4M x 2N), per-wave output 64x64.
// Grid = (M/256)*(N/128) = 256 blocks -> exactly one generation (1 block/CU).
// LDS 96 KiB: 2 dbuf x (A[256][64]=32KB + B[128][64]=16KB); same XOR-chunk swizzle.
// 2 phases/K-tile x 16 MFMA; vmcnt(2) once per K-tile (in-flight [B:2, A:4, B':2]).
template <int EPI>
__global__ __launch_bounds__(512, 2) void gemm8p_n128(const u16* __restrict__ A,
                                                      const u16* __restrict__ BT,
                                                      u16* __restrict__ C,
                                                      const float* __restrict__ bias,
                                                      int M, int N, int K,
                                                      int lda, int ldc) {
    extern __shared__ u16 lds[];  // buf: A 16384 | B 8192 u16; buf stride 24576
    const int tid = threadIdx.x;

    const int ntn = N >> 7;
    int bid = blockIdx.x;
    {
        const int cpx = gridDim.x >> 3;
        bid = (bid & 7) * cpx + (bid >> 3);
    }
    const int tm = (bid / ntn) << 8;
    const int tn = (bid % ntn) << 7;

    const int srow = tid >> 3;
    const int scol = ((tid & 7) ^ (srow & 7)) << 3;
    const u16* Abase = A + (long)(tm + srow) * lda + scol;
    const u16* Bbase = BT + (long)(tn + srow) * (long)K + scol;
    const long lda64 = (long)lda << 6;
    const long ldb64 = (long)K << 6;

    const int nt = K >> 6;

    auto stA = [&](u16* bufbase, int h, int kt) {
        u16* d = bufbase + h * 8192 + tid * 8;
        const u16* g = Abase + (long)(h * 128) * lda + (kt << 6);
        gload_lds16(g, d);
        gload_lds16(g + lda64, d + 4096);
    };
    auto stB = [&](u16* bufbase, int kt) {
        u16* d = bufbase + 16384 + tid * 8;
        const u16* g = Bbase + (kt << 6);
        gload_lds16(g, d);
        gload_lds16(g + ldb64, d + 4096);
    };

    const int wid = tid >> 6, lane = tid & 63;
    const int r16 = lane & 15, q = lane >> 4;
    const int wm = (wid >> 1) * 64;      // 0 / 64 / 128 / 192
    const int wn = (wid & 1) * 64;       // 0 / 64
    const int r7 = r16 & 7;
    const int cx0 = (q ^ r7) << 3;
    const int cx1 = ((4 | q) ^ r7) << 3;
    const int aoff = (wm + r16) * 64;
    const int boff = 16384 + (wn + r16) * 64;

    f32x4 acc[4][4];
#pragma unroll
    for (int i = 0; i < 4; i++)
#pragma unroll
        for (int j = 0; j < 4; j++) acc[i][j] = (f32x4){0.f, 0.f, 0.f, 0.f};

    // prologue: buf0 <- tile0 (A,B); buf1.B <- tile1
    {
        const int t1 = nt > 1 ? 1 : 0;
        stA(lds, 0, 0);
        stA(lds, 1, 0);
        stB(lds, 0);
        stB(lds + 24576, t1);
    }

    for (int it = 0; it < nt; ++it) {
        u16* sb = lds + (it & 1) * 24576;
        u16* so = lds + ((it & 1) ^ 1) * 24576;
        const int tA = (it + 1 < nt) ? it + 1 : nt - 1;
        const int tB = (it + 2 < nt) ? it + 2 : nt - 1;

        asm volatile("s_waitcnt vmcnt(2)" ::: "memory");
        __builtin_amdgcn_s_barrier();

        f16x8 vb[4][2];
#pragma unroll
        for (int ni = 0; ni < 4; ni++) {
            vb[ni][0] = *(const f16x8*)(sb + boff + ni * 1024 + cx0);
            vb[ni][1] = *(const f16x8*)(sb + boff + ni * 1024 + cx1);
        }

#pragma unroll
        for (int p = 0; p < 2; ++p) {
            f16x8 pa[2][2];
#pragma unroll
            for (int m2 = 0; m2 < 2; m2++) {
                pa[m2][0] = *(const f16x8*)(sb + aoff + (2 * p + m2) * 1024 + cx0);
                pa[m2][1] = *(const f16x8*)(sb + aoff + (2 * p + m2) * 1024 + cx1);
            }
            if (p == 0) {
                stA(so, 0, tA);
            } else {
                stA(so, 1, tA);
                stB(sb, tB);
            }
            __builtin_amdgcn_s_barrier();
            asm volatile("s_waitcnt lgkmcnt(0)" ::: "memory");
            __builtin_amdgcn_s_setprio(1);
#pragma unroll
            for (int m2 = 0; m2 < 2; m2++)
#pragma unroll
                for (int ni = 0; ni < 4; ni++) {
                    acc[2 * p + m2][ni] = __builtin_amdgcn_mfma_f32_16x16x32_f16(
                        pa[m2][0], vb[ni][0], acc[2 * p + m2][ni], 0, 0, 0);
                    acc[2 * p + m2][ni] = __builtin_amdgcn_mfma_f32_16x16x32_f16(
                        pa[m2][1], vb[ni][1], acc[2 * p + m2][ni], 0, 0, 0);
                }
            __builtin_amdgcn_s_setprio(0);
            __builtin_amdgcn_s_barrier();
        }
    }

    asm volatile("s_waitcnt vmcnt(0)" ::: "memory");

#pragma unroll
    for (int mi = 0; mi < 4; mi++) {
#pragma unroll
        for (int ni = 0; ni < 4; ni++) {
            const int gcol = tn + wn + ni * 16 + r16;
            float bv = 0.f;
            if (EPI) bv = bias[gcol];
#pragma unroll
            for (int j = 0; j < 4; j++) {
                const int grow = tm + wm + mi * 16 + q * 4 + j;
                float v = acc[mi][ni][j];
                if (EPI) v += bv;
                if (EPI == 1) v = gelu_fast(v);
                C[(long)grow * ldc + gcol] = f2h(v);
            }
        }
    }
}

// ---------------- a_c transform helper ----------------
__device__ __forceinline__ void a_transform(float ar, float ai, float& cr, float& ci) {
    float m = sqrtf(ar * ar + ai * ai);
    float sg = 1.f / (1.f + __expf(-m));
    float sc = sg / fmaxf(m, 1e-30f);
    cr = ar * sc;
    ci = ai * sc;
}

// pcat column offsets: Q=0, K=1024, V=2048, AR=3072, AI=4096, G=5120; row stride PW.
// ---------------- scan phase 1: per-chunk reduce (4 ch/thread, ushort4 loads) ----------
__global__ __launch_bounds__(256) void scan1(const u16* __restrict__ pcat,
                                             float4* __restrict__ sum4) {
    const int b = blockIdx.y, c = blockIdx.x;
    const int d0 = threadIdx.x << 2;
    float Arp[4], Aip[4], Xr[4], Xi[4];
#pragma unroll
    for (int j = 0; j < 4; j++) { Arp[j] = 1.f; Aip[j] = 0.f; Xr[j] = 0.f; Xi[j] = 0.f; }
    const long rowbase = (long)b * Ss + (long)c * TCH;
#pragma unroll 2
    for (int s = 0; s < TCH; ++s) {
        const long ro = (rowbase + s) * PW;
        ushort4 uar = *(const ushort4*)(pcat + ro + 3072 + d0);
        ushort4 uai = *(const ushort4*)(pcat + ro + 4096 + d0);
        ushort4 ukk = *(const ushort4*)(pcat + ro + 1024 + d0);
        ushort4 uvv = *(const ushort4*)(pcat + ro + 2048 + d0);
        const u16* ear = (const u16*)&uar;
        const u16* eai = (const u16*)&uai;
        const u16* ekk = (const u16*)&ukk;
        const u16* evv = (const u16*)&uvv;
#pragma unroll
        for (int j = 0; j < 4; j++) {
            float cr, ci;
            a_transform(h2f(ear[j]), h2f(eai[j]), cr, ci);
            float kv = h2f(ekk[j]) * h2f(evv[j]);
            float nXr = cr * Xr[j] - ci * Xi[j] + kv;
            float nXi = cr * Xi[j] + ci * Xr[j];
            Xr[j] = nXr; Xi[j] = nXi;
            float nAr = cr * Arp[j] - ci * Aip[j];
            float nAi = cr * Aip[j] + ci * Arp[j];
            Arp[j] = nAr; Aip[j] = nAi;
        }
    }
    const long sbase = ((long)b * NCH + c) * 1024 + d0;
#pragma unroll
    for (int j = 0; j < 4; j++)
        sum4[sbase + j] = make_float4(Arp[j], Aip[j], Xr[j], Xi[j]);
}

// ---------------- scan phase 2: sequential carry across chunks ----------------
__global__ __launch_bounds__(256) void scan2(const float4* __restrict__ sum4,
                                             float2* __restrict__ carry) {
    const int idx = blockIdx.x * 256 + threadIdx.x;  // 0..2047
    const int b = idx >> 10, d = idx & 1023;
    float hr = 0.f, hi = 0.f;
    for (int cb = 0; cb < NCH / 8; ++cb) {
        float4 t[8];
#pragma unroll
        for (int j = 0; j < 8; j++)
            t[j] = sum4[((long)b * NCH + cb * 8 + j) * 1024 + d];
#pragma unroll
        for (int j = 0; j < 8; j++) {
            carry[((long)b * NCH + cb * 8 + j) * 1024 + d] = make_float2(hr, hi);
            float nr = t[j].x * hr - t[j].y * hi + t[j].z;
            float ni = t[j].x * hi + t[j].y * hr + t[j].w;
            hr = nr; hi = ni;
        }
    }
}

// -------- scan phase 3: re-scan with carry, fused silu/q gating; y over Q in-place ------
__global__ __launch_bounds__(256) void scan3(u16* pcat,
                                             const float2* __restrict__ carry) {
    const int b = blockIdx.y, c = blockIdx.x;
    const int d0 = threadIdx.x << 2;
    float hr[4], hi[4];
    const long cbase = ((long)b * NCH + c) * 1024 + d0;
#pragma unroll
    for (int j = 0; j < 4; j++) {
        float2 h0 = carry[cbase + j];
        hr[j] = h0.x; hi[j] = h0.y;
    }
    const long rowbase = (long)b * Ss + (long)c * TCH;
#pragma unroll 2
    for (int s = 0; s < TCH; ++s) {
        const long ro = (rowbase + s) * PW;
        ushort4 uar = *(const ushort4*)(pcat + ro + 3072 + d0);
        ushort4 uai = *(const ushort4*)(pcat + ro + 4096 + d0);
        ushort4 ukk = *(const ushort4*)(pcat + ro + 1024 + d0);
        ushort4 uvv = *(const ushort4*)(pcat + ro + 2048 + d0);
        ushort4 ugg = *(const ushort4*)(pcat + ro + 5120 + d0);
        ushort4 uqq = *(const ushort4*)(pcat + ro + d0);
        const u16* ear = (const u16*)&uar;
        const u16* eai = (const u16*)&uai;
        const u16* ekk = (const u16*)&ukk;
        const u16* evv = (const u16*)&uvv;
        const u16* egg = (const u16*)&ugg;
        const u16* eqq = (const u16*)&uqq;
        ushort4 oy;
        u16* ey = (u16*)&oy;
#pragma unroll
        for (int j = 0; j < 4; j++) {
            float cr, ci;
            a_transform(h2f(ear[j]), h2f(eai[j]), cr, ci);
            float kv = h2f(ekk[j]) * h2f(evv[j]);
            float nhr = cr * hr[j] - ci * hi[j] + kv;
            float nhi = cr * hi[j] + ci * hr[j];
            hr[j] = nhr; hi[j] = nhi;
            float gg = h2f(egg[j]);
            float si = gg / (1.f + __expf(-gg));
            ey[j] = f2h(h2f(eqq[j]) * nhr * si);
        }
        *(ushort4*)(pcat + ro + d0) = oy;
    }
}

// ---------------- layernorm: out = LN(a + res) * scale + bias ----------------
// a: fp16 (stride sa). RESF32: res fp32 (stride sres). OUTF32: out fp32 (stride sout).
template <int RESF32, int OUTF32>
__global__ __launch_bounds__(256) void ln_kernel(const u16* __restrict__ a, int sa,
                                                 const void* __restrict__ bres, int sres,
                                                 const float* __restrict__ scale,
                                                 const float* __restrict__ bias,
                                                 void* __restrict__ out, int sout) {
    const int row = blockIdx.x;
    const int tid = threadIdx.x;
    const long abase = (long)row * sa;
    const long rbase = (long)row * sres;
    const long obase = (long)row * sout;
    const int d0 = tid * 4;
    float v[4];
    ushort4 ua = *(const ushort4*)(a + abase + d0);
    const u16* ea = (const u16*)&ua;
    if (RESF32) {
        float4 rf = *(const float4*)((const float*)bres + rbase + d0);
        v[0] = h2f(ea[0]) + rf.x; v[1] = h2f(ea[1]) + rf.y;
        v[2] = h2f(ea[2]) + rf.z; v[3] = h2f(ea[3]) + rf.w;
    } else {
        ushort4 ur = *(const ushort4*)((const u16*)bres + rbase + d0);
        const u16* er = (const u16*)&ur;
#pragma unroll
        for (int j = 0; j < 4; j++) v[j] = h2f(ea[j]) + h2f(er[j]);
    }
    float s = v[0] + v[1] + v[2] + v[3];
    float s2 = v[0] * v[0] + v[1] * v[1] + v[2] * v[2] + v[3] * v[3];
#pragma unroll
    for (int off = 32; off; off >>= 1) {
        s += __shfl_down(s, off);
        s2 += __shfl_down(s2, off);
    }
    __shared__ float red[8];
    const int w = tid >> 6, lane = tid & 63;
    if (lane == 0) { red[w] = s; red[4 + w] = s2; }
    __syncthreads();
    if (tid == 0) {
        float ts = red[0] + red[1] + red[2] + red[3];
        float ts2 = red[4] + red[5] + red[6] + red[7];
        float mu = ts * (1.f / 1024.f);
        float var = ts2 * (1.f / 1024.f) - mu * mu;
        red[0] = mu;
        red[1] = rsqrtf(var + 1e-6f);
    }
    __syncthreads();
    const float mu = red[0], rs = red[1];
    float4 sc = *(const float4*)(scale + d0);
    float4 bi = *(const float4*)(bias + d0);
    float y0 = (v[0] - mu) * rs * sc.x + bi.x;
    float y1 = (v[1] - mu) * rs * sc.y + bi.y;
    float y2 = (v[2] - mu) * rs * sc.z + bi.z;
    float y3 = (v[3] - mu) * rs * sc.w + bi.w;
    if (OUTF32) {
        *(float4*)((float*)out + obase + d0) = make_float4(y0, y1, y2, y3);
    } else {
        ushort4 o;
        o.x = f2h(y0); o.y = f2h(y1); o.z = f2h(y2); o.w = f2h(y3);
        *(ushort4*)((u16*)out + obase + d0) = o;
    }
}

extern "C" void kernel_launch(void* const* d_in, const int* in_sizes, int n_in,
                              void* d_out, int out_size, void* d_ws, size_t ws_size,
                              hipStream_t stream) {
    const float* x    = (const float*)d_in[0];
    const float* Wq   = (const float*)d_in[1];
    const float* Wk   = (const float*)d_in[2];
    const float* Wv   = (const float*)d_in[3];
    const float* Wa   = (const float*)d_in[4];
    const float* Wg   = (const float*)d_in[5];
    const float* Wo   = (const float*)d_in[6];
    const float* ln1s = (const float*)d_in[7];
    const float* ln1b = (const float*)d_in[8];
    const float* W1   = (const float*)d_in[9];
    const float* b1   = (const float*)d_in[10];
    const float* W2   = (const float*)d_in[11];
    const float* b2   = (const float*)d_in[12];
    const float* ln2s = (const float*)d_in[13];
    const float* ln2b = (const float*)d_in[14];

    // ---- workspace layout (u16 elements), 142 MiB total ----
    u16* ws    = (u16*)d_ws;
    u16* xb    = ws;                        // 8M   x as fp16
    u16* WTcat = xb + (8u << 20);           // 6M   [6144,1024] fused proj weights^T
    u16* WTo   = WTcat + (6u << 20);        // 1M
    u16* WT1   = WTo + (1u << 20);          // 4M
    u16* WT2   = WT1 + (4u << 20);          // 4M
    u16* pcat  = WT2 + (4u << 20);          // 48M  [8192,6144] everything lives here
    // total = 71M u16 = 142 MiB

    // scan scratch overlays WTcat (dead after the fused projection GEMM):
    // sum4 = 2*256*1024*16B = 8 MiB; carry = 2*256*1024*8B = 4 MiB -> 12 MiB total
    float4* sum4  = (float4*)WTcat;                // 8 MiB
    float2* carry = (float2*)(WTcat + (4u << 20)); // 4 MiB @ +8 MiB

    // allow big dynamic LDS for the 8-phase GEMMs (once; host-side, capture-safe)
    static bool attr_done = false;
    if (!attr_done) {
        hipFuncSetAttribute(reinterpret_cast<const void*>(&gemm8p<0>),
                            hipFuncAttributeMaxDynamicSharedMemorySize, 131072);
        hipFuncSetAttribute(reinterpret_cast<const void*>(&gemm8p<1>),
                            hipFuncAttributeMaxDynamicSharedMemorySize, 131072);
        hipFuncSetAttribute(reinterpret_cast<const void*>(&gemm8p_n128<0>),
                            hipFuncAttributeMaxDynamicSharedMemorySize, 98304);
        hipFuncSetAttribute(reinterpret_cast<const void*>(&gemm8p_n128<2>),
                            hipFuncAttributeMaxDynamicSharedMemorySize, 98304);
        attr_done = true;
    }

    // pcat column slices (row stride PW=6144):
    //   Q=+0  K=+1024  V=+2048  AR=+3072  AI=+4096  G=+5120
    // liveness ladder: scan3 writes y over Q; Wo-GEMM Q->K(o1); LN1 K->Q(yln);
    // FFN1 Q->cols[2048,6144)(hmat); FFN2 hmat->K(o2); LN2 (K,Q)->d_out.

    // fused prep: x->fp16 + all weight transposes (one launch)
    prep_fused<<<dim3(23552), dim3(256), 0, stream>>>(x, xb, Wq, Wk, Wv, Wa, Wg, Wo,
                                                      W1, W2, WTcat, WTo, WT1, WT2);

    // fused q|k|v|a|g projection: [8192,1024] @ [1024,6144] -> pcat
    // persistent 256 blocks x 3 tiles (768 total)
    gemm8p<0><<<dim3(256), dim3(512), 131072, stream>>>(xb, WTcat, pcat, nullptr,
                                                        Mtok, PW, 1024, 1024, PW);
    // gate-loop scan (vectorized: 256 thr x 4 ch, NCH=256 chunks of 16)
    scan1<<<dim3(NCH, Bb), dim3(256), 0, stream>>>(pcat, sum4);
    scan2<<<dim3(8), dim3(256), 0, stream>>>(sum4, carry);
    scan3<<<dim3(NCH, Bb), dim3(256), 0, stream>>>(pcat, carry);
    // output proj: y(Q slice) @ Wo -> o1(K slice)   (256x128 8-phase, 256 blocks)
    gemm8p_n128<0><<<dim3(256), dim3(512), 98304, stream>>>(pcat, WTo, pcat + 1024,
                                                            nullptr,
                                                            Mtok, 1024, 1024, PW, PW);
    // LN1: o1 + x -> yln(Q slice)
    ln_kernel<1, 0><<<dim3(Mtok), dim3(256), 0, stream>>>(pcat + 1024, PW, x, 1024,
                                                          ln1s, ln1b, pcat, PW);
    // FFN1: yln @ W1 + b1, gelu -> hmat(cols 2048..6144)
    // persistent 256 blocks x 2 tiles (512 total)
    gemm8p<1><<<dim3(256), dim3(512), 131072, stream>>>(pcat, WT1, pcat + 2048, b1,
                                                        Mtok, Ff, 1024, PW, PW);
    // FFN2: hmat @ W2 + b2 -> o2(K slice)   (256x128 8-phase, 256 blocks, 64 K-tiles)
    gemm8p_n128<2><<<dim3(256), dim3(512), 98304, stream>>>(pcat + 2048, WT2,
                                                            pcat + 1024, b2,
                                                            Mtok, 1024, Ff, PW, PW);
    // LN2: o2 + yln -> fp32 d_out
    ln_kernel<0, 1><<<dim3(Mtok), dim3(256), 0, stream>>>(pcat + 1024, PW, pcat, PW,
                                                          ln2s, ln2b, d_out, 1024);
}

// Round 5
// 513.393 us; speedup vs baseline: 1.0671x; 1.0671x over previous
//
#include <hip/hip_runtime.h>
#include <cstdint>

typedef unsigned short u16;
typedef unsigned int u32;

#define AS1 __attribute__((address_space(1)))
#define AS3 __attribute__((address_space(3)))

typedef _Float16 f16x8 __attribute__((ext_vector_type(8)));
typedef float f32x4 __attribute__((ext_vector_type(4)));

static constexpr int Bb = 2, Ss = 4096, Dd = 1024, Ff = 4096;
static constexpr int Mtok = Bb * Ss;          // 8192
static constexpr int NCH = 128;               // scan chunks per sequence (256 regressed scan2)
static constexpr int TCH = Ss / NCH;          // 32 steps per chunk
static constexpr int PW = 6144;               // fused projection width / pcat row stride

__device__ __forceinline__ float h2f(u16 u) {
    union { u16 u; _Float16 h; } w; w.u = u; return (float)w.h;
}
__device__ __forceinline__ u16 f2h(float f) {
    union { _Float16 h; u16 u; } w; w.h = (_Float16)f; return w.u;
}

// fast gelu(tanh) == v * sigmoid(1.595769122*(v + 0.044715 v^3))  (exact identity)
__device__ __forceinline__ float gelu_fast(float v) {
    float u = 1.5957691216057308f * (v + 0.044715f * v * v * v);
    return v / (1.f + __expf(-u));
}

// async global->LDS, 16 B per lane (m97 pattern; addrspacecast via C-cast)
__device__ __forceinline__ void gload_lds16(const u16* g, u16* l) {
    __builtin_amdgcn_global_load_lds((const AS1 u32*)g, (AS3 u32*)l, 16, 0, 0);
}

// ============ fused prep: x->fp16 + all 8 weight transposes, ONE launch ============
__global__ __launch_bounds__(256) void prep_fused(
    const float* __restrict__ x, u16* __restrict__ xb,
    const float* __restrict__ Wq, const float* __restrict__ Wk,
    const float* __restrict__ Wv, const float* __restrict__ Wa,
    const float* __restrict__ Wg, const float* __restrict__ Wo,
    const float* __restrict__ W1, const float* __restrict__ W2,
    u16* __restrict__ WTcat, u16* __restrict__ WTo,
    u16* __restrict__ WT1, u16* __restrict__ WT2) {
    __shared__ u16 t[32][33];
    const int tid = threadIdx.x;
    const int idx = blockIdx.x;
    if (idx < 8192) {
        const long i = ((long)idx * 256 + tid) * 4;
        float4 f = *(const float4*)(x + i);
        ushort4 o;
        o.x = f2h(f.x); o.y = f2h(f.y); o.z = f2h(f.z); o.w = f2h(f.w);
        *(ushort4*)(xb + i) = o;
        return;
    }
    const float* src; u16* dst; int K, N, ti;
    if (idx < 9216)       { src = Wq; dst = WTcat;             K = 1024; N = 1024; ti = idx - 8192; }
    else if (idx < 10240) { src = Wk; dst = WTcat + (1u << 20); K = 1024; N = 1024; ti = idx - 9216; }
    else if (idx < 11264) { src = Wv; dst = WTcat + (2u << 20); K = 1024; N = 1024; ti = idx - 10240; }
    else if (idx < 13312) { src = Wa; dst = WTcat + (3u << 20); K = 1024; N = 2048; ti = idx - 11264; }
    else if (idx < 14336) { src = Wg; dst = WTcat + (5u << 20); K = 1024; N = 1024; ti = idx - 13312; }
    else if (idx < 15360) { src = Wo; dst = WTo;               K = 1024; N = 1024; ti = idx - 14336; }
    else if (idx < 19456) { src = W1; dst = WT1;               K = 1024; N = 4096; ti = idx - 15360; }
    else                  { src = W2; dst = WT2;               K = 4096; N = 1024; ti = idx - 19456; }
    const int tiles_x = N >> 5;
    const int bx = ti % tiles_x, by = ti / tiles_x;
    const int n0 = bx << 5, k0 = by << 5;
    const int tx = tid & 31, ty = tid >> 5;   // ty 0..7
#pragma unroll
    for (int r = 0; r < 4; r++) {
        const int row = ty + r * 8;
        t[row][tx] = f2h(src[(long)(k0 + row) * N + n0 + tx]);
    }
    __syncthreads();
    // packed u32 stores: lane owns 2 consecutive k (cx, cx+1) for rows ry, ry+16
    const int cx = (tid & 15) << 1;
    const int ry = tid >> 4;                  // 0..15
#pragma unroll
    for (int r = 0; r < 2; r++) {
        const int row = ry + r * 16;
        u32 v = (u32)t[cx][row] | ((u32)t[cx + 1][row] << 16);
        *(u32*)(dst + (long)(n0 + row) * K + k0 + cx) = v;
    }
}

// ============== 256x256 GEMM, PERSISTENT, 2 phases per K-tile ==============
// BM=BN=256, BK=64, 512 threads = 8 waves (2M x 4N), per-wave output 128x64.
// LDS 128 KiB: 2 dbuf x (A[256][64] + B[256][64]) fp16, XOR-swizzled 16B chunks:
//   element (row,k) lives at chunk (k>>3) ^ (row&7)  -> conflict-free ds_read_b128.
// global_load_lds writes linearly -> pre-swizzle the global SOURCE column (rule 21).
// PERSISTENT: each block owns tpb tiles; tail staging redirects to next tile
// (nt even => buffer parity continuous across the seam).
// Per K-tile, 2 phases x 32 MFMA (was 4 x 16 -- halves barrier/lgkm drains):
//   p0: read vb(8)+pa[mi0..3](8); stage A(it+1) -> so; bar; lgkm0; 32 MFMA; bar
//   p1: read pa[mi4..7](8);       stage B(it+2) -> sb; bar; lgkm0; 32 MFMA; bar
// Ledger unchanged: in-flight at iter top = [B(it):4, A(it):4, B(it+1):4] -> vmcnt(4).
// WAR: stB(sb) issues after p0-end barrier, by which all waves' vb reads completed.
template <int EPI>
__global__ __launch_bounds__(512, 2) void gemm8p(const u16* __restrict__ A,
                                                 const u16* __restrict__ BT,
                                                 u16* __restrict__ C,
                                                 const float* __restrict__ bias,
                                                 int M, int N, int K,
                                                 int lda, int ldc) {
    extern __shared__ u16 lds[];  // [buf0: A 16384 | B 16384][buf1: A | B] u16
    const int tid = threadIdx.x;

    const int ntn = N >> 8;
    const int total = (M >> 8) * ntn;     // output tiles (multiple of 8 and of grid)
    const int tpb = total / (int)gridDim.x;
    const int cpx = total >> 3;           // XCD-bijective swizzle chunk

    const int srow = tid >> 3;                          // 0..63 within a 64-row round
    const int scol = ((tid & 7) ^ (srow & 7)) << 3;     // swizzled k-chunk * 8
    const long lda64 = (long)lda << 6;   // 64 rows of A
    const long ldb64 = (long)K << 6;     // 64 rows of B^T

    const int nt = K >> 6;

    auto bases_for = [&](int t, int& tm, int& tn, const u16*& Ab, const u16*& Bb) {
        if (t > tpb - 1) t = tpb - 1;
        const int ti = (int)blockIdx.x + t * (int)gridDim.x;
        const int b = (ti & 7) * cpx + (ti >> 3);
        tm = (b / ntn) << 8;
        tn = (b % ntn) << 8;
        Ab = A + (long)(tm + srow) * lda + scol;
        Bb = BT + (long)(tn + srow) * (long)K + scol;
    };

    auto stA = [&](u16* bufbase, int h, const u16* Ab, int kt) {
        u16* d = bufbase + h * 8192 + tid * 8;
        const u16* g = Ab + (long)(h * 128) * lda + (kt << 6);
        gload_lds16(g, d);
        gload_lds16(g + lda64, d + 4096);
    };
    auto stB = [&](u16* bufbase, int h, const u16* Bb, int kt) {
        u16* d = bufbase + 16384 + h * 8192 + tid * 8;
        const u16* g = Bb + (long)(h * 128) * (long)K + (kt << 6);
        gload_lds16(g, d);
        gload_lds16(g + ldb64, d + 4096);
    };

    const int wid = tid >> 6, lane = tid & 63;
    const int r16 = lane & 15, q = lane >> 4;
    const int wm = (wid >> 2) * 128;     // 0 / 128
    const int wn = (wid & 3) * 64;       // 0 / 64 / 128 / 192
    const int r7 = r16 & 7;
    const int cx0 = (q ^ r7) << 3;        // k-half 0 chunk offset (u16)
    const int cx1 = ((4 | q) ^ r7) << 3;  // k-half 1
    const int aoff = (wm + r16) * 64;
    const int boff = 16384 + (wn + r16) * 64;

    f32x4 acc[8][4];
#pragma unroll
    for (int i = 0; i < 8; i++)
#pragma unroll
        for (int j = 0; j < 4; j++) acc[i][j] = (f32x4){0.f, 0.f, 0.f, 0.f};

    int tmc, tnc, tmn, tnn;
    const u16 *Ac, *Bc, *An, *Bn;
    bases_for(0, tmc, tnc, Ac, Bc);
    bases_for(1, tmn, tnn, An, Bn);

    // ---- prologue: buf0 <- tile0.kt0 (A,B), buf1.B <- tile0.kt1 ----
    stA(lds, 0, Ac, 0);
    stA(lds, 1, Ac, 0);
    stB(lds, 0, Bc, 0);
    stB(lds, 1, Bc, 0);
    stB(lds + 32768, 0, Bc, 1);
    stB(lds + 32768, 1, Bc, 1);

    for (int t = 0; t < tpb; ++t) {
        for (int it = 0; it < nt; ++it) {
            u16* sb = lds + ((it & 1) << 15);          // current buffer (nt even)
            u16* so = lds + (((it & 1) ^ 1) << 15);    // other buffer

            asm volatile("s_waitcnt vmcnt(4)" ::: "memory");
            __builtin_amdgcn_s_barrier();

            // ---------------- phase 0: mi 0..3 ----------------
            f16x8 vb[4][2];
#pragma unroll
            for (int ni = 0; ni < 4; ni++) {
                vb[ni][0] = *(const f16x8*)(sb + boff + ni * 1024 + cx0);
                vb[ni][1] = *(const f16x8*)(sb + boff + ni * 1024 + cx1);
            }
            f16x8 pa[4][2];
#pragma unroll
            for (int m = 0; m < 4; m++) {
                pa[m][0] = *(const f16x8*)(sb + aoff + m * 1024 + cx0);
                pa[m][1] = *(const f16x8*)(sb + aoff + m * 1024 + cx1);
            }
            if (it + 1 < nt) {
                stA(so, 0, Ac, it + 1);
                stA(so, 1, Ac, it + 1);
            } else {
                stA(so, 0, An, 0);
                stA(so, 1, An, 0);
            }
            __builtin_amdgcn_s_barrier();
            asm volatile("s_waitcnt lgkmcnt(0)" ::: "memory");
            __builtin_amdgcn_s_setprio(1);
#pragma unroll
            for (int m = 0; m < 4; m++)
#pragma unroll
                for (int ni = 0; ni < 4; ni++) {
                    acc[m][ni] = __builtin_amdgcn_mfma_f32_16x16x32_f16(
                        pa[m][0], vb[ni][0], acc[m][ni], 0, 0, 0);
                    acc[m][ni] = __builtin_amdgcn_mfma_f32_16x16x32_f16(
                        pa[m][1], vb[ni][1], acc[m][ni], 0, 0, 0);
                }
            __builtin_amdgcn_s_setprio(0);
            __builtin_amdgcn_s_barrier();

            // ---------------- phase 1: mi 4..7 ----------------
#pragma unroll
            for (int m = 0; m < 4; m++) {
                pa[m][0] = *(const f16x8*)(sb + aoff + (4 + m) * 1024 + cx0);
                pa[m][1] = *(const f16x8*)(sb + aoff + (4 + m) * 1024 + cx1);
            }
            if (it + 2 < nt) {
                stB(sb, 0, Bc, it + 2);
                stB(sb, 1, Bc, it + 2);
            } else {
                stB(sb, 0, Bn, it + 2 - nt);
                stB(sb, 1, Bn, it + 2 - nt);
            }
            __builtin_amdgcn_s_barrier();
            asm volatile("s_waitcnt lgkmcnt(0)" ::: "memory");
            __builtin_amdgcn_s_setprio(1);
#pragma unroll
            for (int m = 0; m < 4; m++)
#pragma unroll
                for (int ni = 0; ni < 4; ni++) {
                    acc[4 + m][ni] = __builtin_amdgcn_mfma_f32_16x16x32_f16(
                        pa[m][0], vb[ni][0], acc[4 + m][ni], 0, 0, 0);
                    acc[4 + m][ni] = __builtin_amdgcn_mfma_f32_16x16x32_f16(
                        pa[m][1], vb[ni][1], acc[4 + m][ni], 0, 0, 0);
                }
            __builtin_amdgcn_s_setprio(0);
            __builtin_amdgcn_s_barrier();
        }

        // ---- epilogue for tile t (stores drain under the next tile's vmcnt) ----
#pragma unroll
        for (int mi = 0; mi < 8; mi++) {
#pragma unroll
            for (int ni = 0; ni < 4; ni++) {
                const int gcol = tnc + wn + ni * 16 + r16;
                float bv = 0.f;
                if (EPI) bv = bias[gcol];
#pragma unroll
                for (int j = 0; j < 4; j++) {
                    const int grow = tmc + wm + mi * 16 + q * 4 + j;
                    float v = acc[mi][ni][j];
                    if (EPI) v += bv;
                    if (EPI == 1) v = gelu_fast(v);
                    C[(long)grow * ldc + gcol] = f2h(v);
                    acc[mi][ni][j] = 0.f;
                }
            }
        }
        tmc = tmn; tnc = tnn; Ac = An; Bc = Bn;
        bases_for(t + 2, tmn, tnn, An, Bn);
    }

    asm volatile("s_waitcnt vmcnt(0)" ::: "memory");
}

// ================== 256x128 8-phase GEMM variant (narrow-N: Wo, FFN2) ==================
// BM=256, BN=128, BK=64, 512 threads = 8 waves (4M x 2N), per-wave output 64x64.
// Grid = (M/256)*(N/128) = 256 blocks -> exactly one generation (1 block/CU).
// LDS 96 KiB: 2 dbuf x (A[256][64]=32KB + B[128][64]=16KB); same XOR-chunk swizzle.
// 2 phases/K-tile x 16 MFMA; vmcnt(2) once per K-tile (in-flight [B:2, A:4, B':2]).
template <int EPI>
__global__ __launch_bounds__(512, 2) void gemm8p_n128(const u16* __restrict__ A,
                                                      const u16* __restrict__ BT,
                                                      u16* __restrict__ C,
                                                      const float* __restrict__ bias,
                                                      int M, int N, int K,
                                                      int lda, int ldc) {
    extern __shared__ u16 lds[];  // buf: A 16384 | B 8192 u16; buf stride 24576
    const int tid = threadIdx.x;

    const int ntn = N >> 7;
    int bid = blockIdx.x;
    {
        const int cpx = gridDim.x >> 3;
        bid = (bid & 7) * cpx + (bid >> 3);
    }
    const int tm = (bid / ntn) << 8;
    const int tn = (bid % ntn) << 7;

    const int srow = tid >> 3;
    const int scol = ((tid & 7) ^ (srow & 7)) << 3;
    const u16* Abase = A + (long)(tm + srow) * lda + scol;
    const u16* Bbase = BT + (long)(tn + srow) * (long)K + scol;
    const long lda64 = (long)lda << 6;
    const long ldb64 = (long)K << 6;

    const int nt = K >> 6;

    auto stA = [&](u16* bufbase, int h, int kt) {
        u16* d = bufbase + h * 8192 + tid * 8;
        const u16* g = Abase + (long)(h * 128) * lda + (kt << 6);
        gload_lds16(g, d);
        gload_lds16(g + lda64, d + 4096);
    };
    auto stB = [&](u16* bufbase, int kt) {
        u16* d = bufbase + 16384 + tid * 8;
        const u16* g = Bbase + (kt << 6);
        gload_lds16(g, d);
        gload_lds16(g + ldb64, d + 4096);
    };

    const int wid = tid >> 6, lane = tid & 63;
    const int r16 = lane & 15, q = lane >> 4;
    const int wm = (wid >> 1) * 64;      // 0 / 64 / 128 / 192
    const int wn = (wid & 1) * 64;       // 0 / 64
    const int r7 = r16 & 7;
    const int cx0 = (q ^ r7) << 3;
    const int cx1 = ((4 | q) ^ r7) << 3;
    const int aoff = (wm + r16) * 64;
    const int boff = 16384 + (wn + r16) * 64;

    f32x4 acc[4][4];
#pragma unroll
    for (int i = 0; i < 4; i++)
#pragma unroll
        for (int j = 0; j < 4; j++) acc[i][j] = (f32x4){0.f, 0.f, 0.f, 0.f};

    // prologue: buf0 <- tile0 (A,B); buf1.B <- tile1
    {
        const int t1 = nt > 1 ? 1 : 0;
        stA(lds, 0, 0);
        stA(lds, 1, 0);
        stB(lds, 0);
        stB(lds + 24576, t1);
    }

    for (int it = 0; it < nt; ++it) {
        u16* sb = lds + (it & 1) * 24576;
        u16* so = lds + ((it & 1) ^ 1) * 24576;
        const int tA = (it + 1 < nt) ? it + 1 : nt - 1;
        const int tB = (it + 2 < nt) ? it + 2 : nt - 1;

        asm volatile("s_waitcnt vmcnt(2)" ::: "memory");
        __builtin_amdgcn_s_barrier();

        f16x8 vb[4][2];
#pragma unroll
        for (int ni = 0; ni < 4; ni++) {
            vb[ni][0] = *(const f16x8*)(sb + boff + ni * 1024 + cx0);
            vb[ni][1] = *(const f16x8*)(sb + boff + ni * 1024 + cx1);
        }

#pragma unroll
        for (int p = 0; p < 2; ++p) {
            f16x8 pa[2][2];
#pragma unroll
            for (int m2 = 0; m2 < 2; m2++) {
                pa[m2][0] = *(const f16x8*)(sb + aoff + (2 * p + m2) * 1024 + cx0);
                pa[m2][1] = *(const f16x8*)(sb + aoff + (2 * p + m2) * 1024 + cx1);
            }
            if (p == 0) {
                stA(so, 0, tA);
            } else {
                stA(so, 1, tA);
                stB(sb, tB);
            }
            __builtin_amdgcn_s_barrier();
            asm volatile("s_waitcnt lgkmcnt(0)" ::: "memory");
            __builtin_amdgcn_s_setprio(1);
#pragma unroll
            for (int m2 = 0; m2 < 2; m2++)
#pragma unroll
                for (int ni = 0; ni < 4; ni++) {
                    acc[2 * p + m2][ni] = __builtin_amdgcn_mfma_f32_16x16x32_f16(
                        pa[m2][0], vb[ni][0], acc[2 * p + m2][ni], 0, 0, 0);
                    acc[2 * p + m2][ni] = __builtin_amdgcn_mfma_f32_16x16x32_f16(
                        pa[m2][1], vb[ni][1], acc[2 * p + m2][ni], 0, 0, 0);
                }
            __builtin_amdgcn_s_setprio(0);
            __builtin_amdgcn_s_barrier();
        }
    }

    asm volatile("s_waitcnt vmcnt(0)" ::: "memory");

#pragma unroll
    for (int mi = 0; mi < 4; mi++) {
#pragma unroll
        for (int ni = 0; ni < 4; ni++) {
            const int gcol = tn + wn + ni * 16 + r16;
            float bv = 0.f;
            if (EPI) bv = bias[gcol];
#pragma unroll
            for (int j = 0; j < 4; j++) {
                const int grow = tm + wm + mi * 16 + q * 4 + j;
                float v = acc[mi][ni][j];
                if (EPI) v += bv;
                if (EPI == 1) v = gelu_fast(v);
                C[(long)grow * ldc + gcol] = f2h(v);
            }
        }
    }
}

// ---------------- a_c transform helper ----------------
__device__ __forceinline__ void a_transform(float ar, float ai, float& cr, float& ci) {
    float m = sqrtf(ar * ar + ai * ai);
    float sg = 1.f / (1.f + __expf(-m));
    float sc = sg / fmaxf(m, 1e-30f);
    cr = ar * sc;
    ci = ai * sc;
}

// pcat column offsets: Q=0, K=1024, V=2048, AR=3072, AI=4096, G=5120; row stride PW.
// ---------------- scan phase 1: per-chunk reduce (4 ch/thread, ushort4 loads) ----------
__global__ __launch_bounds__(256) void scan1(const u16* __restrict__ pcat,
                                             float4* __restrict__ sum4) {
    const int b = blockIdx.y, c = blockIdx.x;
    const int d0 = threadIdx.x << 2;
    float Arp[4], Aip[4], Xr[4], Xi[4];
#pragma unroll
    for (int j = 0; j < 4; j++) { Arp[j] = 1.f; Aip[j] = 0.f; Xr[j] = 0.f; Xi[j] = 0.f; }
    const long rowbase = (long)b * Ss + (long)c * TCH;
#pragma unroll 2
    for (int s = 0; s < TCH; ++s) {
        const long ro = (rowbase + s) * PW;
        ushort4 uar = *(const ushort4*)(pcat + ro + 3072 + d0);
        ushort4 uai = *(const ushort4*)(pcat + ro + 4096 + d0);
        ushort4 ukk = *(const ushort4*)(pcat + ro + 1024 + d0);
        ushort4 uvv = *(const ushort4*)(pcat + ro + 2048 + d0);
        const u16* ear = (const u16*)&uar;
        const u16* eai = (const u16*)&uai;
        const u16* ekk = (const u16*)&ukk;
        const u16* evv = (const u16*)&uvv;
#pragma unroll
        for (int j = 0; j < 4; j++) {
            float cr, ci;
            a_transform(h2f(ear[j]), h2f(eai[j]), cr, ci);
            float kv = h2f(ekk[j]) * h2f(evv[j]);
            float nXr = cr * Xr[j] - ci * Xi[j] + kv;
            float nXi = cr * Xi[j] + ci * Xr[j];
            Xr[j] = nXr; Xi[j] = nXi;
            float nAr = cr * Arp[j] - ci * Aip[j];
            float nAi = cr * Aip[j] + ci * Arp[j];
            Arp[j] = nAr; Aip[j] = nAi;
        }
    }
    const long sbase = ((long)b * NCH + c) * 1024 + d0;
#pragma unroll
    for (int j = 0; j < 4; j++)
        sum4[sbase + j] = make_float4(Arp[j], Aip[j], Xr[j], Xi[j]);
}

// ---------------- scan phase 2: sequential carry across chunks ----------------
__global__ __launch_bounds__(256) void scan2(const float4* __restrict__ sum4,
                                             float2* __restrict__ carry) {
    const int idx = blockIdx.x * 256 + threadIdx.x;  // 0..2047
    const int b = idx >> 10, d = idx & 1023;
    float hr = 0.f, hi = 0.f;
    for (int cb = 0; cb < NCH / 8; ++cb) {
        float4 t[8];
#pragma unroll
        for (int j = 0; j < 8; j++)
            t[j] = sum4[((long)b * NCH + cb * 8 + j) * 1024 + d];
#pragma unroll
        for (int j = 0; j < 8; j++) {
            carry[((long)b * NCH + cb * 8 + j) * 1024 + d] = make_float2(hr, hi);
            float nr = t[j].x * hr - t[j].y * hi + t[j].z;
            float ni = t[j].x * hi + t[j].y * hr + t[j].w;
            hr = nr; hi = ni;
        }
    }
}

// -------- scan phase 3: re-scan with carry, fused silu/q gating; y over Q in-place ------
__global__ __launch_bounds__(256) void scan3(u16* pcat,
                                             const float2* __restrict__ carry) {
    const int b = blockIdx.y, c = blockIdx.x;
    const int d0 = threadIdx.x << 2;
    float hr[4], hi[4];
    const long cbase = ((long)b * NCH + c) * 1024 + d0;
#pragma unroll
    for (int j = 0; j < 4; j++) {
        float2 h0 = carry[cbase + j];
        hr[j] = h0.x; hi[j] = h0.y;
    }
    const long rowbase = (long)b * Ss + (long)c * TCH;
#pragma unroll 2
    for (int s = 0; s < TCH; ++s) {
        const long ro = (rowbase + s) * PW;
        ushort4 uar = *(const ushort4*)(pcat + ro + 3072 + d0);
        ushort4 uai = *(const ushort4*)(pcat + ro + 4096 + d0);
        ushort4 ukk = *(const ushort4*)(pcat + ro + 1024 + d0);
        ushort4 uvv = *(const ushort4*)(pcat + ro + 2048 + d0);
        ushort4 ugg = *(const ushort4*)(pcat + ro + 5120 + d0);
        ushort4 uqq = *(const ushort4*)(pcat + ro + d0);
        const u16* ear = (const u16*)&uar;
        const u16* eai = (const u16*)&uai;
        const u16* ekk = (const u16*)&ukk;
        const u16* evv = (const u16*)&uvv;
        const u16* egg = (const u16*)&ugg;
        const u16* eqq = (const u16*)&uqq;
        ushort4 oy;
        u16* ey = (u16*)&oy;
#pragma unroll
        for (int j = 0; j < 4; j++) {
            float cr, ci;
            a_transform(h2f(ear[j]), h2f(eai[j]), cr, ci);
            float kv = h2f(ekk[j]) * h2f(evv[j]);
            float nhr = cr * hr[j] - ci * hi[j] + kv;
            float nhi = cr * hi[j] + ci * hr[j];
            hr[j] = nhr; hi[j] = nhi;
            float gg = h2f(egg[j]);
            float si = gg / (1.f + __expf(-gg));
            ey[j] = f2h(h2f(eqq[j]) * nhr * si);
        }
        *(ushort4*)(pcat + ro + d0) = oy;
    }
}

// ---------------- layernorm: out = LN(a + res) * scale + bias ----------------
// a: fp16 (stride sa). RESF32: res fp32 (stride sres). OUTF32: out fp32 (stride sout).
template <int RESF32, int OUTF32>
__global__ __launch_bounds__(256) void ln_kernel(const u16* __restrict__ a, int sa,
                                                 const void* __restrict__ bres, int sres,
                                                 const float* __restrict__ scale,
                                                 const float* __restrict__ bias,
                                                 void* __restrict__ out, int sout) {
    const int row = blockIdx.x;
    const int tid = threadIdx.x;
    const long abase = (long)row * sa;
    const long rbase = (long)row * sres;
    const long obase = (long)row * sout;
    const int d0 = tid * 4;
    float v[4];
    ushort4 ua = *(const ushort4*)(a + abase + d0);
    const u16* ea = (const u16*)&ua;
    if (RESF32) {
        float4 rf = *(const float4*)((const float*)bres + rbase + d0);
        v[0] = h2f(ea[0]) + rf.x; v[1] = h2f(ea[1]) + rf.y;
        v[2] = h2f(ea[2]) + rf.z; v[3] = h2f(ea[3]) + rf.w;
    } else {
        ushort4 ur = *(const ushort4*)((const u16*)bres + rbase + d0);
        const u16* er = (const u16*)&ur;
#pragma unroll
        for (int j = 0; j < 4; j++) v[j] = h2f(ea[j]) + h2f(er[j]);
    }
    float s = v[0] + v[1] + v[2] + v[3];
    float s2 = v[0] * v[0] + v[1] * v[1] + v[2] * v[2] + v[3] * v[3];
#pragma unroll
    for (int off = 32; off; off >>= 1) {
        s += __shfl_down(s, off);
        s2 += __shfl_down(s2, off);
    }
    __shared__ float red[8];
    const int w = tid >> 6, lane = tid & 63;
    if (lane == 0) { red[w] = s; red[4 + w] = s2; }
    __syncthreads();
    if (tid == 0) {
        float ts = red[0] + red[1] + red[2] + red[3];
        float ts2 = red[4] + red[5] + red[6] + red[7];
        float mu = ts * (1.f / 1024.f);
        float var = ts2 * (1.f / 1024.f) - mu * mu;
        red[0] = mu;
        red[1] = rsqrtf(var + 1e-6f);
    }
    __syncthreads();
    const float mu = red[0], rs = red[1];
    float4 sc = *(const float4*)(scale + d0);
    float4 bi = *(const float4*)(bias + d0);
    float y0 = (v[0] - mu) * rs * sc.x + bi.x;
    float y1 = (v[1] - mu) * rs * sc.y + bi.y;
    float y2 = (v[2] - mu) * rs * sc.z + bi.z;
    float y3 = (v[3] - mu) * rs * sc.w + bi.w;
    if (OUTF32) {
        *(float4*)((float*)out + obase + d0) = make_float4(y0, y1, y2, y3);
    } else {
        ushort4 o;
        o.x = f2h(y0); o.y = f2h(y1); o.z = f2h(y2); o.w = f2h(y3);
        *(ushort4*)((u16*)out + obase + d0) = o;
    }
}

extern "C" void kernel_launch(void* const* d_in, const int* in_sizes, int n_in,
                              void* d_out, int out_size, void* d_ws, size_t ws_size,
                              hipStream_t stream) {
    const float* x    = (const float*)d_in[0];
    const float* Wq   = (const float*)d_in[1];
    const float* Wk   = (const float*)d_in[2];
    const float* Wv   = (const float*)d_in[3];
    const float* Wa   = (const float*)d_in[4];
    const float* Wg   = (const float*)d_in[5];
    const float* Wo   = (const float*)d_in[6];
    const float* ln1s = (const float*)d_in[7];
    const float* ln1b = (const float*)d_in[8];
    const float* W1   = (const float*)d_in[9];
    const float* b1   = (const float*)d_in[10];
    const float* W2   = (const float*)d_in[11];
    const float* b2   = (const float*)d_in[12];
    const float* ln2s = (const float*)d_in[13];
    const float* ln2b = (const float*)d_in[14];

    // ---- workspace layout (u16 elements), 142 MiB total ----
    u16* ws    = (u16*)d_ws;
    u16* xb    = ws;                        // 8M   x as fp16
    u16* WTcat = xb + (8u << 20);           // 6M   [6144,1024] fused proj weights^T
    u16* WTo   = WTcat + (6u << 20);        // 1M
    u16* WT1   = WTo + (1u << 20);          // 4M
    u16* WT2   = WT1 + (4u << 20);          // 4M
    u16* pcat  = WT2 + (4u << 20);          // 48M  [8192,6144] everything lives here
    // total = 71M u16 = 142 MiB

    // scan scratch overlays WTcat (dead after the fused projection GEMM):
    // sum4 = 2*128*1024*16B = 4 MiB; carry = 2 MiB
    float4* sum4  = (float4*)WTcat;                // 4 MiB
    float2* carry = (float2*)(WTcat + (2u << 20)); // 2 MiB @ +4 MiB

    // allow big dynamic LDS for the 8-phase GEMMs (once; host-side, capture-safe)
    static bool attr_done = false;
    if (!attr_done) {
        hipFuncSetAttribute(reinterpret_cast<const void*>(&gemm8p<0>),
                            hipFuncAttributeMaxDynamicSharedMemorySize, 131072);
        hipFuncSetAttribute(reinterpret_cast<const void*>(&gemm8p<1>),
                            hipFuncAttributeMaxDynamicSharedMemorySize, 131072);
        hipFuncSetAttribute(reinterpret_cast<const void*>(&gemm8p_n128<0>),
                            hipFuncAttributeMaxDynamicSharedMemorySize, 98304);
        hipFuncSetAttribute(reinterpret_cast<const void*>(&gemm8p_n128<2>),
                            hipFuncAttributeMaxDynamicSharedMemorySize, 98304);
        attr_done = true;
    }

    // pcat column slices (row stride PW=6144):
    //   Q=+0  K=+1024  V=+2048  AR=+3072  AI=+4096  G=+5120
    // liveness ladder: scan3 writes y over Q; Wo-GEMM Q->K(o1); LN1 K->Q(yln);
    // FFN1 Q->cols[2048,6144)(hmat); FFN2 hmat->K(o2); LN2 (K,Q)->d_out.

    // fused prep: x->fp16 + all weight transposes (one launch)
    prep_fused<<<dim3(23552), dim3(256), 0, stream>>>(x, xb, Wq, Wk, Wv, Wa, Wg, Wo,
                                                      W1, W2, WTcat, WTo, WT1, WT2);

    // fused q|k|v|a|g projection: [8192,1024] @ [1024,6144] -> pcat
    // persistent 256 blocks x 3 tiles (768 total)
    gemm8p<0><<<dim3(256), dim3(512), 131072, stream>>>(xb, WTcat, pcat, nullptr,
                                                        Mtok, PW, 1024, 1024, PW);
    // gate-loop scan (vectorized: 256 thr x 4 ch, NCH=128 chunks of 32)
    scan1<<<dim3(NCH, Bb), dim3(256), 0, stream>>>(pcat, sum4);
    scan2<<<dim3(8), dim3(256), 0, stream>>>(sum4, carry);
    scan3<<<dim3(NCH, Bb), dim3(256), 0, stream>>>(pcat, carry);
    // output proj: y(Q slice) @ Wo -> o1(K slice)   (256x128 8-phase, 256 blocks)
    gemm8p_n128<0><<<dim3(256), dim3(512), 98304, stream>>>(pcat, WTo, pcat + 1024,
                                                            nullptr,
                                                            Mtok, 1024, 1024, PW, PW);
    // LN1: o1 + x -> yln(Q slice)
    ln_kernel<1, 0><<<dim3(Mtok), dim3(256), 0, stream>>>(pcat + 1024, PW, x, 1024,
                                                          ln1s, ln1b, pcat, PW);
    // FFN1: yln @ W1 + b1, gelu -> hmat(cols 2048..6144)
    // persistent 256 blocks x 2 tiles (512 total)
    gemm8p<1><<<dim3(256), dim3(512), 131072, stream>>>(pcat, WT1, pcat + 2048, b1,
                                                        Mtok, Ff, 1024, PW, PW);
    // FFN2: hmat @ W2 + b2 -> o2(K slice)   (256x128 8-phase, 256 blocks, 64 K-tiles)
    gemm8p_n128<2><<<dim3(256), dim3(512), 98304, stream>>>(pcat + 2048, WT2,
                                                            pcat + 1024, b2,
                                                            Mtok, 1024, Ff, PW, PW);
    // LN2: o2 + yln -> fp32 d_out
    ln_kernel<0, 1><<<dim3(Mtok), dim3(256), 0, stream>>>(pcat + 1024, PW, pcat, PW,
                                                          ln2s, ln2b, d_out, 1024);
}